// Round 6
// baseline (93.550 us; speedup 1.0000x reference)
//
#include <hip/hip_runtime.h>
#include <hip/hip_bf16.h>
#include <stdint.h>

// HashedLinear: C[1024][4096] = x[1024][4096] @ w[indx[4096][4096]] + b
#define M_DIM 1024
#define K_DIM 4096
#define N_DIM 4096
#define NW    65536

typedef __bf16 bf16x8 __attribute__((ext_vector_type(8)));
typedef float  f32x16 __attribute__((ext_vector_type(16)));

// float -> bf16 round-to-nearest-even (bit trick; inputs are normal floats)
__device__ __forceinline__ unsigned short f2bf(float f) {
  unsigned u = __float_as_uint(f);
  u += 0x7fffu + ((u >> 16) & 1u);
  return (unsigned short)(u >> 16);
}

__device__ __forceinline__ void load_lds16(const void* g, void* l) {
  __builtin_amdgcn_global_load_lds((const __attribute__((address_space(1))) void*)g,
                                   (__attribute__((address_space(3))) void*)l,
                                   16, 0, 0);
}

// ---- kernel 1: convert x and w to bf16 (stored as ushort) ----
__global__ void prep_kernel(const float* __restrict__ x, const float* __restrict__ w,
                            unsigned short* __restrict__ xb, unsigned short* __restrict__ wb) {
  const int XQ = M_DIM * K_DIM / 4;
  const int WQ = NW / 4;
  int i = blockIdx.x * blockDim.x + threadIdx.x;
  if (i < XQ) {
    float4 v = reinterpret_cast<const float4*>(x)[i];
    ushort4 o;
    o.x = f2bf(v.x); o.y = f2bf(v.y); o.z = f2bf(v.z); o.w = f2bf(v.w);
    reinterpret_cast<ushort4*>(xb)[i] = o;
  } else if (i < XQ + WQ) {
    int j = i - XQ;
    float4 v = reinterpret_cast<const float4*>(w)[j];
    ushort4 o;
    o.x = f2bf(v.x); o.y = f2bf(v.y); o.z = f2bf(v.z); o.w = f2bf(v.w);
    reinterpret_cast<ushort4*>(wb)[j] = o;
  }
}

// ---- kernel 2: gather + transpose with the WHOLE pool staged in LDS ----
// (at its ~15 us streaming roofline: 64 MB indx + 32 MB Bt + pool staging)
__global__ __launch_bounds__(1024)
void gather_kernel(const int* __restrict__ indx,
                   const unsigned short* __restrict__ wb,
                   unsigned short* __restrict__ Bt) {
  __shared__ unsigned short pool[NW];        // 128 KB
  __shared__ unsigned short tile[64][68];    // 8.5 KB
  int t = threadIdx.x;

  {
    const uint4* src = reinterpret_cast<const uint4*>(wb);
    uint4* dst = reinterpret_cast<uint4*>(pool);
#pragma unroll
    for (int i = 0; i < 8; ++i) dst[t + i * 1024] = src[t + i * 1024];
  }

  int r  = t >> 4, cq = t & 15;   // load-phase coords (k-row, n-quad)
  int nn = t >> 4, kq = t & 15;   // write-phase coords (n-row, k-quad)
  int base_tid = blockIdx.x * 16;

  int4 id;
  {
    int k0 = ((base_tid >> 6) << 6), n0 = ((base_tid & 63) << 6);
    id = *reinterpret_cast<const int4*>(indx + (size_t)(k0 + r) * N_DIM + n0 + cq * 4);
  }
  __syncthreads();  // pool ready

  for (int it = 0; it < 16; ++it) {
    int tid = base_tid + it;
    int k0 = ((tid >> 6) << 6), n0 = ((tid & 63) << 6);

    int4 idn = id;
    if (it < 15) {
      int tid2 = tid + 1;
      int k02 = ((tid2 >> 6) << 6), n02 = ((tid2 & 63) << 6);
      idn = *reinterpret_cast<const int4*>(indx + (size_t)(k02 + r) * N_DIM + n02 + cq * 4);
    }

    tile[r][cq * 4 + 0] = pool[id.x];
    tile[r][cq * 4 + 1] = pool[id.y];
    tile[r][cq * 4 + 2] = pool[id.z];
    tile[r][cq * 4 + 3] = pool[id.w];
    __syncthreads();

    ushort4 o;
    o.x = tile[kq * 4 + 0][nn];
    o.y = tile[kq * 4 + 1][nn];
    o.z = tile[kq * 4 + 2][nn];
    o.w = tile[kq * 4 + 3][nn];
    *reinterpret_cast<ushort4*>(Bt + (size_t)(n0 + nn) * K_DIM + k0 + kq * 4) = o;
    __syncthreads();

    id = idn;
  }
}

// ---- kernel 3: bf16 MFMA GEMM, 128x128 tile, 32x32x16 MFMA, wave tile 64x64 ----
// LDS-traffic-optimized: reads/MFMA halved vs 64x32 wave tile. Counted-vmcnt
// dbuf skeleton retained from prior round (race-free, verified).
#define BM 128
#define BN 128
#define BK 64

__global__ __launch_bounds__(256)
void gemm_kernel(const unsigned short* __restrict__ A,   // x bf16 [M][K]
                 const unsigned short* __restrict__ Bt,  // B^T bf16 [N][K]
                 const float* __restrict__ bias,
                 float* __restrict__ C) {                // [M][N] f32
  __shared__ unsigned short As[2][BM * BK];  // 2 x 16 KB
  __shared__ unsigned short Bs[2][BN * BK];  // 2 x 16 KB

  int t = threadIdx.x;
  int lane = t & 63, wid = t >> 6;
  int wm = wid >> 1, wn = wid & 1;        // 2x2 wave grid; wave tile 64x64
  int ln31 = lane & 31, lhi = lane >> 5;  // 32x32 frag: row=ln31, k-chunk=lhi

  // XCD swizzle: grid 256 (%8==0). XCD x gets swz in [x*32, x*32+32):
  // by in [x*4, x*4+4) (4 B-panels = 4 MB, L2-resident), bx all 8 (A re-read
  // from L2/L3, only 8 MB total).
  int bid = blockIdx.x;
  int swz = (bid & 7) * 32 + (bid >> 3);
  int bx = swz & 7, by = swz >> 3;        // bx: M-tile (8), by: N-tile (32)
  int m0 = bx * BM, n0 = by * BN;

  const unsigned short* Ag = A  + (size_t)m0 * K_DIM;
  const unsigned short* Bg = Bt + (size_t)n0 * K_DIM;

  f32x16 acc[2][2];
#pragma unroll
  for (int i = 0; i < 2; ++i)
#pragma unroll
    for (int j = 0; j < 2; ++j)
      acc[i][j] = (f32x16)(0.f);

  // Staging: LDS linear (global_load_lds requirement); swizzle by permuting
  // the GLOBAL source 16B-chunk: LDS slot s holds global chunk s^(r&7).
  // A and B tiles are both 128 rows x 8 chunks = 1024 chunks; 4 per thread.
#define STAGE(buf, kb)                                                        \
  do {                                                                        \
    _Pragma("unroll")                                                         \
    for (int i_ = 0; i_ < 4; ++i_) {                                          \
      int c_ = t + i_ * 256;                                                  \
      int r_ = c_ >> 3, s_ = c_ & 7;                                          \
      load_lds16(Ag + (size_t)r_ * K_DIM + (kb) + ((s_ ^ (r_ & 7)) << 3),     \
                 (char*)As[buf] + c_ * 16);                                   \
    }                                                                         \
    _Pragma("unroll")                                                         \
    for (int i_ = 0; i_ < 4; ++i_) {                                          \
      int c_ = t + i_ * 256;                                                  \
      int r_ = c_ >> 3, s_ = c_ & 7;                                          \
      load_lds16(Bg + (size_t)r_ * K_DIM + (kb) + ((s_ ^ (r_ & 7)) << 3),     \
                 (char*)Bs[buf] + c_ * 16);                                   \
    }                                                                         \
  } while (0)

  STAGE(0, 0);  // 8 loads in flight

  const int NT = K_DIM / BK;  // 64
  for (int kt = 0; kt < NT; ++kt) {
    int cur = kt & 1;
    if (kt + 1 < NT) {
      STAGE(cur ^ 1, (kt + 1) * BK);                    // 16 in flight
      asm volatile("s_waitcnt vmcnt(8)" ::: "memory");  // oldest 8 (=cur) done
    } else {
      asm volatile("s_waitcnt vmcnt(0)" ::: "memory");  // final tile: drain
    }
    __builtin_amdgcn_sched_barrier(0);
    __builtin_amdgcn_s_barrier();   // raw: no vmcnt(0) drain attached
    __builtin_amdgcn_sched_barrier(0);

    // 4 k-slices of 16; per slice: 2 A frags + 2 B frags -> 4 MFMAs
#pragma unroll
    for (int kk = 0; kk < 4; ++kk) {
      bf16x8 af[2], bfv[2];
#pragma unroll
      for (int mi = 0; mi < 2; ++mi) {
        int row = wm * 64 + mi * 32 + ln31;
        int q = (kk * 2 + lhi) ^ (row & 7);
        af[mi] = *reinterpret_cast<const bf16x8*>((char*)As[cur] + row * 128 + q * 16);
      }
#pragma unroll
      for (int ni = 0; ni < 2; ++ni) {
        int row = wn * 64 + ni * 32 + ln31;
        int q = (kk * 2 + lhi) ^ (row & 7);
        bfv[ni] = *reinterpret_cast<const bf16x8*>((char*)Bs[cur] + row * 128 + q * 16);
      }
#pragma unroll
      for (int mi = 0; mi < 2; ++mi)
#pragma unroll
        for (int ni = 0; ni < 2; ++ni)
          acc[mi][ni] = __builtin_amdgcn_mfma_f32_32x32x16_bf16(af[mi], bfv[ni], acc[mi][ni], 0, 0, 0);
    }
    __builtin_amdgcn_sched_barrier(0);
    __builtin_amdgcn_s_barrier();   // all waves done reading cur before next
    __builtin_amdgcn_sched_barrier(0);  // iter's STAGE overwrites cur^1
  }

  // epilogue: 32x32 C/D layout (m74/m101): col = lane&31,
  // row = (reg&3) + 8*(reg>>2) + 4*(lane>>5)
#pragma unroll
  for (int ni = 0; ni < 2; ++ni) {
    int gc = n0 + wn * 64 + ni * 32 + ln31;
    float bv = bias[gc];
#pragma unroll
    for (int mi = 0; mi < 2; ++mi) {
      int base = m0 + wm * 64 + mi * 32 + 4 * lhi;
#pragma unroll
      for (int r = 0; r < 16; ++r) {
        int gr = base + (r & 3) + 8 * (r >> 2);
        C[(size_t)gr * N_DIM + gc] = acc[mi][ni][r] + bv;
      }
    }
  }
#undef STAGE
}

extern "C" void kernel_launch(void* const* d_in, const int* in_sizes, int n_in,
                              void* d_out, int out_size, void* d_ws, size_t ws_size,
                              hipStream_t stream) {
  const float* x    = (const float*)d_in[0];
  const float* w    = (const float*)d_in[1];
  const float* b    = (const float*)d_in[2];
  const int*   indx = (const int*)d_in[3];
  float* out = (float*)d_out;

  // workspace: xb (8 MB) | wb (128 KB) | Bt (32 MB)
  unsigned short* xb = (unsigned short*)d_ws;
  unsigned short* wb = xb + (size_t)M_DIM * K_DIM;
  unsigned short* Bt = wb + NW;

  int prep_total = (M_DIM * K_DIM + NW) / 4;
  prep_kernel<<<(prep_total + 255) / 256, 256, 0, stream>>>(x, w, xb, wb);
  gather_kernel<<<256, 1024, 0, stream>>>(indx, wb, Bt);
  gemm_kernel<<<256, 256, 0, stream>>>(xb, Bt, b, out);
}

// Round 7
// 82.170 us; speedup vs baseline: 1.1385x; 1.1385x over previous
//
#include <hip/hip_runtime.h>
#include <hip/hip_bf16.h>
#include <stdint.h>

// HashedLinear: C[1024][4096] = x[1024][4096] @ w[indx[4096][4096]] + b
#define M_DIM 1024
#define K_DIM 4096
#define N_DIM 4096
#define NW    65536

typedef __bf16 bf16x8 __attribute__((ext_vector_type(8)));
typedef float  f32x4  __attribute__((ext_vector_type(4)));

// float -> bf16 round-to-nearest-even (bit trick; inputs are normal floats)
__device__ __forceinline__ unsigned short f2bf(float f) {
  unsigned u = __float_as_uint(f);
  u += 0x7fffu + ((u >> 16) & 1u);
  return (unsigned short)(u >> 16);
}

__device__ __forceinline__ void load_lds16(const void* g, void* l) {
  __builtin_amdgcn_global_load_lds((const __attribute__((address_space(1))) void*)g,
                                   (__attribute__((address_space(3))) void*)l,
                                   16, 0, 0);
}

// ---- kernel 1: convert x and w to bf16 (stored as ushort) ----
__global__ void prep_kernel(const float* __restrict__ x, const float* __restrict__ w,
                            unsigned short* __restrict__ xb, unsigned short* __restrict__ wb) {
  const int XQ = M_DIM * K_DIM / 4;
  const int WQ = NW / 4;
  int i = blockIdx.x * blockDim.x + threadIdx.x;
  if (i < XQ) {
    float4 v = reinterpret_cast<const float4*>(x)[i];
    ushort4 o;
    o.x = f2bf(v.x); o.y = f2bf(v.y); o.z = f2bf(v.z); o.w = f2bf(v.w);
    reinterpret_cast<ushort4*>(xb)[i] = o;
  } else if (i < XQ + WQ) {
    int j = i - XQ;
    float4 v = reinterpret_cast<const float4*>(w)[j];
    ushort4 o;
    o.x = f2bf(v.x); o.y = f2bf(v.y); o.z = f2bf(v.z); o.w = f2bf(v.w);
    reinterpret_cast<ushort4*>(wb)[j] = o;
  }
}

// ---- kernel 2: gather + transpose with the WHOLE pool staged in LDS ----
// (at its ~15 us streaming roofline: 64 MB indx + 32 MB Bt + pool staging)
__global__ __launch_bounds__(1024)
void gather_kernel(const int* __restrict__ indx,
                   const unsigned short* __restrict__ wb,
                   unsigned short* __restrict__ Bt) {
  __shared__ unsigned short pool[NW];        // 128 KB
  __shared__ unsigned short tile[64][68];    // 8.5 KB
  int t = threadIdx.x;

  {
    const uint4* src = reinterpret_cast<const uint4*>(wb);
    uint4* dst = reinterpret_cast<uint4*>(pool);
#pragma unroll
    for (int i = 0; i < 8; ++i) dst[t + i * 1024] = src[t + i * 1024];
  }

  int r  = t >> 4, cq = t & 15;   // load-phase coords (k-row, n-quad)
  int nn = t >> 4, kq = t & 15;   // write-phase coords (n-row, k-quad)
  int base_tid = blockIdx.x * 16;

  int4 id;
  {
    int k0 = ((base_tid >> 6) << 6), n0 = ((base_tid & 63) << 6);
    id = *reinterpret_cast<const int4*>(indx + (size_t)(k0 + r) * N_DIM + n0 + cq * 4);
  }
  __syncthreads();  // pool ready

  for (int it = 0; it < 16; ++it) {
    int tid = base_tid + it;
    int k0 = ((tid >> 6) << 6), n0 = ((tid & 63) << 6);

    int4 idn = id;
    if (it < 15) {
      int tid2 = tid + 1;
      int k02 = ((tid2 >> 6) << 6), n02 = ((tid2 & 63) << 6);
      idn = *reinterpret_cast<const int4*>(indx + (size_t)(k02 + r) * N_DIM + n02 + cq * 4);
    }

    tile[r][cq * 4 + 0] = pool[id.x];
    tile[r][cq * 4 + 1] = pool[id.y];
    tile[r][cq * 4 + 2] = pool[id.z];
    tile[r][cq * 4 + 3] = pool[id.w];
    __syncthreads();

    ushort4 o;
    o.x = tile[kq * 4 + 0][nn];
    o.y = tile[kq * 4 + 1][nn];
    o.z = tile[kq * 4 + 2][nn];
    o.w = tile[kq * 4 + 3][nn];
    *reinterpret_cast<ushort4*>(Bt + (size_t)(n0 + nn) * K_DIM + k0 + kq * 4) = o;
    __syncthreads();

    id = idn;
  }
}

// ---- kernel 3: bf16 MFMA GEMM, TRIPLE-buffered, prefetch distance 2 ----
// Steady state: 18 loads in flight (tiles t, t+1, t+2); vmcnt(12) waits only
// for tile t, whose loads were issued TWO compute phases (~800 cyc) earlier.
// 12 loads stay in flight across every barrier (never drain to 0 mid-loop).
// Geometry/fragment pattern = R3/R5 verified (conflict-free, 2 blocks/CU).
#define BM 128
#define BN 64
#define BK 64

__global__ __launch_bounds__(256, 2)
void gemm_kernel(const unsigned short* __restrict__ A,   // x bf16 [M][K]
                 const unsigned short* __restrict__ Bt,  // B^T bf16 [N][K]
                 const float* __restrict__ bias,
                 float* __restrict__ C) {                // [M][N] f32
  __shared__ unsigned short As[3][BM * BK];  // 3 x 16 KB
  __shared__ unsigned short Bs[3][BN * BK];  // 3 x 8 KB

  int t = threadIdx.x;
  int lane = t & 63, wid = t >> 6;
  int wm = wid >> 1, wn = wid & 1;        // 2x2 wave grid; wave tile 64x32

  // XCD swizzle (512 blocks, 512%8==0)
  int bid = blockIdx.x;
  int swz = (bid & 7) * 64 + (bid >> 3);
  int bx = swz & 7, by = swz >> 3;        // bx: M-tile (8), by: N-tile (64)
  int m0 = bx * BM, n0 = by * BN;

  const unsigned short* Ag = A  + (size_t)m0 * K_DIM;
  const unsigned short* Bg = Bt + (size_t)n0 * K_DIM;

  f32x4 acc[4][2];
#pragma unroll
  for (int i = 0; i < 4; ++i)
#pragma unroll
    for (int j = 0; j < 2; ++j)
      acc[i][j] = (f32x4){0.f, 0.f, 0.f, 0.f};

  int fr = lane & 15, hc = lane >> 4;     // frag row, k-half-chunk

  // Staging: LDS linear (global_load_lds requirement); swizzle by permuting
  // the GLOBAL source 16B-chunk: LDS slot s holds global chunk s^(r&7).
#define STAGE(adst, bdst, kb)                                                 \
  do {                                                                        \
    _Pragma("unroll")                                                         \
    for (int i_ = 0; i_ < 4; ++i_) {                                          \
      int c_ = t + i_ * 256;                                                  \
      int r_ = c_ >> 3, s_ = c_ & 7;                                          \
      load_lds16(Ag + (size_t)r_ * K_DIM + (kb) + ((s_ ^ (r_ & 7)) << 3),     \
                 (char*)(adst) + c_ * 16);                                    \
    }                                                                         \
    _Pragma("unroll")                                                         \
    for (int i_ = 0; i_ < 2; ++i_) {                                          \
      int c_ = t + i_ * 256;                                                  \
      int r_ = c_ >> 3, s_ = c_ & 7;                                          \
      load_lds16(Bg + (size_t)r_ * K_DIM + (kb) + ((s_ ^ (r_ & 7)) << 3),     \
                 (char*)(bdst) + c_ * 16);                                    \
    }                                                                         \
  } while (0)

  // buffer rotation via pointer swap (no runtime %3; rule #20)
  unsigned short *a0 = As[0], *a1 = As[1], *a2 = As[2];
  unsigned short *b0 = Bs[0], *b1 = Bs[1], *b2 = Bs[2];

  STAGE(a0, b0, 0);        //  6 in flight (tile 0)
  STAGE(a1, b1, BK);       // 12 in flight (tiles 0,1)

  const int NT = K_DIM / BK;  // 64
  for (int kt = 0; kt < NT; ++kt) {
    if (kt + 2 < NT) {
      STAGE(a2, b2, (kt + 2) * BK);                      // 18 in flight
      asm volatile("s_waitcnt vmcnt(12)" ::: "memory");  // tile kt done
    } else if (kt + 1 < NT) {
      asm volatile("s_waitcnt vmcnt(6)" ::: "memory");   // tile kt done
    } else {
      asm volatile("s_waitcnt vmcnt(0)" ::: "memory");   // last tile: drain
    }
    __builtin_amdgcn_s_barrier();   // raw: 12 loads stay in flight
    __builtin_amdgcn_sched_barrier(0);  // fence: no ds_read hoists above

#pragma unroll
    for (int kk = 0; kk < 2; ++kk) {
      bf16x8 af[4], bfv[2];
#pragma unroll
      for (int mi = 0; mi < 4; ++mi) {
        int row = wm * 64 + mi * 16 + fr;
        int q = (hc + kk * 4) ^ (row & 7);   // logical chunk ^ row swizzle
        af[mi] = *reinterpret_cast<const bf16x8*>((char*)a0 + row * 128 + q * 16);
      }
#pragma unroll
      for (int ni = 0; ni < 2; ++ni) {
        int row = wn * 32 + ni * 16 + fr;
        int q = (hc + kk * 4) ^ (row & 7);
        bfv[ni] = *reinterpret_cast<const bf16x8*>((char*)b0 + row * 128 + q * 16);
      }
#pragma unroll
      for (int mi = 0; mi < 4; ++mi)
#pragma unroll
        for (int ni = 0; ni < 2; ++ni)
          acc[mi][ni] = __builtin_amdgcn_mfma_f32_16x16x32_bf16(af[mi], bfv[ni], acc[mi][ni], 0, 0, 0);
    }
    __builtin_amdgcn_sched_barrier(0);
    __builtin_amdgcn_s_barrier();   // all waves done reading a0/b0 before the
                                    // next iteration's STAGE overwrites them

    // rotate: a0 <- a1 <- a2 <- a0
    unsigned short* ta = a0; a0 = a1; a1 = a2; a2 = ta;
    unsigned short* tb = b0; b0 = b1; b1 = b2; b2 = tb;
  }

  // epilogue: C/D layout col = lane&15, row = (lane>>4)*4 + j  (m89-verified)
  int fq = lane >> 4;
#pragma unroll
  for (int ni = 0; ni < 2; ++ni) {
    int gc = n0 + wn * 32 + ni * 16 + fr;
    float bv = bias[gc];
#pragma unroll
    for (int mi = 0; mi < 4; ++mi) {
      int gr = m0 + wm * 64 + mi * 16 + fq * 4;
#pragma unroll
      for (int j = 0; j < 4; ++j)
        C[(size_t)(gr + j) * N_DIM + gc] = acc[mi][ni][j] + bv;
    }
  }
#undef STAGE
}

extern "C" void kernel_launch(void* const* d_in, const int* in_sizes, int n_in,
                              void* d_out, int out_size, void* d_ws, size_t ws_size,
                              hipStream_t stream) {
  const float* x    = (const float*)d_in[0];
  const float* w    = (const float*)d_in[1];
  const float* b    = (const float*)d_in[2];
  const int*   indx = (const int*)d_in[3];
  float* out = (float*)d_out;

  // workspace: xb (8 MB) | wb (128 KB) | Bt (32 MB)
  unsigned short* xb = (unsigned short*)d_ws;
  unsigned short* wb = xb + (size_t)M_DIM * K_DIM;
  unsigned short* Bt = wb + NW;

  int prep_total = (M_DIM * K_DIM + NW) / 4;
  prep_kernel<<<(prep_total + 255) / 256, 256, 0, stream>>>(x, w, xb, wb);
  gather_kernel<<<256, 1024, 0, stream>>>(indx, wb, Bt);
  gemm_kernel<<<512, 256, 0, stream>>>(xb, Bt, b, out);
}

// Round 8
// 67.136 us; speedup vs baseline: 1.3934x; 1.2239x over previous
//
#include <hip/hip_runtime.h>
#include <hip/hip_bf16.h>
#include <stdint.h>

// HashedLinear: C[1024][4096] = x[1024][4096] @ w[indx[4096][4096]] + b
#define M_DIM 1024
#define K_DIM 4096
#define N_DIM 4096
#define NW    65536

typedef __bf16 bf16x8 __attribute__((ext_vector_type(8)));
typedef float  f32x4  __attribute__((ext_vector_type(4)));

// float -> bf16 round-to-nearest-even (bit trick; inputs are normal floats)
__device__ __forceinline__ unsigned short f2bf(float f) {
  unsigned u = __float_as_uint(f);
  u += 0x7fffu + ((u >> 16) & 1u);
  return (unsigned short)(u >> 16);
}

__device__ __forceinline__ void load_lds16(const void* g, void* l) {
  __builtin_amdgcn_global_load_lds((const __attribute__((address_space(1))) void*)g,
                                   (__attribute__((address_space(3))) void*)l,
                                   16, 0, 0);
}

// ---- kernel 1: convert x and w to bf16 (stored as ushort) ----
__global__ void prep_kernel(const float* __restrict__ x, const float* __restrict__ w,
                            unsigned short* __restrict__ xb, unsigned short* __restrict__ wb) {
  const int XQ = M_DIM * K_DIM / 4;
  const int WQ = NW / 4;
  int i = blockIdx.x * blockDim.x + threadIdx.x;
  if (i < XQ) {
    float4 v = reinterpret_cast<const float4*>(x)[i];
    ushort4 o;
    o.x = f2bf(v.x); o.y = f2bf(v.y); o.z = f2bf(v.z); o.w = f2bf(v.w);
    reinterpret_cast<ushort4*>(xb)[i] = o;
  } else if (i < XQ + WQ) {
    int j = i - XQ;
    float4 v = reinterpret_cast<const float4*>(w)[j];
    ushort4 o;
    o.x = f2bf(v.x); o.y = f2bf(v.y); o.z = f2bf(v.z); o.w = f2bf(v.w);
    reinterpret_cast<ushort4*>(wb)[j] = o;
  }
}

// ---- kernel 2: gather + transpose with the WHOLE pool staged in LDS ----
// (at its ~15 us streaming roofline: 64 MB indx + 32 MB Bt + pool staging)
__global__ __launch_bounds__(1024)
void gather_kernel(const int* __restrict__ indx,
                   const unsigned short* __restrict__ wb,
                   unsigned short* __restrict__ Bt) {
  __shared__ unsigned short pool[NW];        // 128 KB
  __shared__ unsigned short tile[64][68];    // 8.5 KB
  int t = threadIdx.x;

  {
    const uint4* src = reinterpret_cast<const uint4*>(wb);
    uint4* dst = reinterpret_cast<uint4*>(pool);
#pragma unroll
    for (int i = 0; i < 8; ++i) dst[t + i * 1024] = src[t + i * 1024];
  }

  int r  = t >> 4, cq = t & 15;   // load-phase coords (k-row, n-quad)
  int nn = t >> 4, kq = t & 15;   // write-phase coords (n-row, k-quad)
  int base_tid = blockIdx.x * 16;

  int4 id;
  {
    int k0 = ((base_tid >> 6) << 6), n0 = ((base_tid & 63) << 6);
    id = *reinterpret_cast<const int4*>(indx + (size_t)(k0 + r) * N_DIM + n0 + cq * 4);
  }
  __syncthreads();  // pool ready

  for (int it = 0; it < 16; ++it) {
    int tid = base_tid + it;
    int k0 = ((tid >> 6) << 6), n0 = ((tid & 63) << 6);

    int4 idn = id;
    if (it < 15) {
      int tid2 = tid + 1;
      int k02 = ((tid2 >> 6) << 6), n02 = ((tid2 & 63) << 6);
      idn = *reinterpret_cast<const int4*>(indx + (size_t)(k02 + r) * N_DIM + n02 + cq * 4);
    }

    tile[r][cq * 4 + 0] = pool[id.x];
    tile[r][cq * 4 + 1] = pool[id.y];
    tile[r][cq * 4 + 2] = pool[id.z];
    tile[r][cq * 4 + 3] = pool[id.w];
    __syncthreads();

    ushort4 o;
    o.x = tile[kq * 4 + 0][nn];
    o.y = tile[kq * 4 + 1][nn];
    o.z = tile[kq * 4 + 2][nn];
    o.w = tile[kq * 4 + 3][nn];
    *reinterpret_cast<ushort4*>(Bt + (size_t)(n0 + nn) * K_DIM + k0 + kq * 4) = o;
    __syncthreads();

    id = idn;
  }
}

// ---- kernel 3: bf16 MFMA GEMM, 8-wave fine-phase structure ----
// 512 threads (8 waves 2Mx4N), BM=BN=128, BK=64, triple-buffered LDS.
// Per K-step: 2 phases {6 ds_read (kk half) | 2 global_load_lds stage |
// setprio(1) 8 MFMA setprio(0)}, then ONE boundary: counted vmcnt(4)
// (never 0 mid-loop) + raw s_barrier. Fine interleave per m196/m248.
#define BM 128
#define BN 128
#define BK 64

__global__ __launch_bounds__(512)
void gemm_kernel(const unsigned short* __restrict__ A,   // x bf16 [M][K]
                 const unsigned short* __restrict__ Bt,  // B^T bf16 [N][K]
                 const float* __restrict__ bias,
                 float* __restrict__ C) {                // [M][N] f32
  __shared__ unsigned short As[3][BM * BK];  // 3 x 16 KB
  __shared__ unsigned short Bs[3][BN * BK];  // 3 x 16 KB

  int t = threadIdx.x;                // 0..511
  int lane = t & 63, wid = t >> 6;    // 8 waves
  int wm = wid >> 2, wn = wid & 3;    // 2x4 wave grid; wave tile 64x32

  // XCD swizzle: grid 256 (%8==0). XCD x gets by in [x*4, x*4+4): 4 N-panels
  // = 4 MB Bt (L2-resident) and all 8 M-tiles (A = 8 MB, L3-resident).
  int bid = blockIdx.x;
  int swz = (bid & 7) * 32 + (bid >> 3);
  int bx = swz & 7, by = swz >> 3;    // bx: M-tile (8), by: N-tile (32)
  int m0 = bx * BM, n0 = by * BN;

  const unsigned short* Ag = A  + (size_t)m0 * K_DIM;
  const unsigned short* Bg = Bt + (size_t)n0 * K_DIM;

  f32x4 acc[4][2];
#pragma unroll
  for (int i = 0; i < 4; ++i)
#pragma unroll
    for (int j = 0; j < 2; ++j)
      acc[i][j] = (f32x4){0.f, 0.f, 0.f, 0.f};

  int fr = lane & 15, hc = lane >> 4;  // frag row, k-half-chunk

  // Staging: A tile 128 rows x 8 chunks = 1024 chunks, B same; 512 threads
  // -> 2 A-chunks (phase A) + 2 B-chunks (phase B) per thread per K-step.
  // LDS linear dest; swizzle via GLOBAL source chunk permute s^(r&7).
#define STAGE_A(dst, kb)                                                      \
  do {                                                                        \
    _Pragma("unroll")                                                         \
    for (int i_ = 0; i_ < 2; ++i_) {                                          \
      int c_ = t + i_ * 512;                                                  \
      int r_ = c_ >> 3, s_ = c_ & 7;                                          \
      load_lds16(Ag + (size_t)r_ * K_DIM + (kb) + ((s_ ^ (r_ & 7)) << 3),     \
                 (char*)(dst) + c_ * 16);                                     \
    }                                                                         \
  } while (0)
#define STAGE_B(dst, kb)                                                      \
  do {                                                                        \
    _Pragma("unroll")                                                         \
    for (int i_ = 0; i_ < 2; ++i_) {                                          \
      int c_ = t + i_ * 512;                                                  \
      int r_ = c_ >> 3, s_ = c_ & 7;                                          \
      load_lds16(Bg + (size_t)r_ * K_DIM + (kb) + ((s_ ^ (r_ & 7)) << 3),     \
                 (char*)(dst) + c_ * 16);                                     \
    }                                                                         \
  } while (0)

  unsigned short *a0 = As[0], *a1 = As[1], *a2 = As[2];
  unsigned short *b0 = Bs[0], *b1 = Bs[1], *b2 = Bs[2];

  STAGE_A(a0, 0);  STAGE_B(b0, 0);    // 4 in flight (tile 0)
  STAGE_A(a1, BK); STAGE_B(b1, BK);   // 8 in flight (tiles 0,1)
  asm volatile("s_waitcnt vmcnt(4)" ::: "memory");  // tile 0 ready
  __builtin_amdgcn_sched_barrier(0);
  __builtin_amdgcn_s_barrier();
  __builtin_amdgcn_sched_barrier(0);

  const int NT = K_DIM / BK;  // 64
  for (int kt = 0; kt < NT; ++kt) {
    const bool pf = (kt + 2 < NT);
    const int kb2 = (kt + 2) * BK;

    // ---- phase A (kk=0) ----
    {
      bf16x8 af[4], bfv[2];
#pragma unroll
      for (int mi = 0; mi < 4; ++mi) {
        int row = wm * 64 + mi * 16 + fr;
        int q = hc ^ (row & 7);
        af[mi] = *reinterpret_cast<const bf16x8*>((char*)a0 + row * 128 + q * 16);
      }
#pragma unroll
      for (int ni = 0; ni < 2; ++ni) {
        int row = wn * 32 + ni * 16 + fr;
        int q = hc ^ (row & 7);
        bfv[ni] = *reinterpret_cast<const bf16x8*>((char*)b0 + row * 128 + q * 16);
      }
      if (pf) STAGE_A(a2, kb2);
      __builtin_amdgcn_s_setprio(1);
#pragma unroll
      for (int mi = 0; mi < 4; ++mi)
#pragma unroll
        for (int ni = 0; ni < 2; ++ni)
          acc[mi][ni] = __builtin_amdgcn_mfma_f32_16x16x32_bf16(af[mi], bfv[ni], acc[mi][ni], 0, 0, 0);
      __builtin_amdgcn_s_setprio(0);
    }

    // ---- phase B (kk=1) ----
    {
      bf16x8 af[4], bfv[2];
#pragma unroll
      for (int mi = 0; mi < 4; ++mi) {
        int row = wm * 64 + mi * 16 + fr;
        int q = (hc + 4) ^ (row & 7);
        af[mi] = *reinterpret_cast<const bf16x8*>((char*)a0 + row * 128 + q * 16);
      }
#pragma unroll
      for (int ni = 0; ni < 2; ++ni) {
        int row = wn * 32 + ni * 16 + fr;
        int q = (hc + 4) ^ (row & 7);
        bfv[ni] = *reinterpret_cast<const bf16x8*>((char*)b0 + row * 128 + q * 16);
      }
      if (pf) STAGE_B(b2, kb2);
      __builtin_amdgcn_s_setprio(1);
#pragma unroll
      for (int mi = 0; mi < 4; ++mi)
#pragma unroll
        for (int ni = 0; ni < 2; ++ni)
          acc[mi][ni] = __builtin_amdgcn_mfma_f32_16x16x32_bf16(af[mi], bfv[ni], acc[mi][ni], 0, 0, 0);
      __builtin_amdgcn_s_setprio(0);
    }

    // ---- K-step boundary: counted wait (tile kt+1 ready), one barrier ----
    if (pf) {
      asm volatile("s_waitcnt vmcnt(4)" ::: "memory");  // kt+2's 4 stay in flight
    } else {
      asm volatile("s_waitcnt vmcnt(0)" ::: "memory");  // tail: drain
    }
    __builtin_amdgcn_sched_barrier(0);
    __builtin_amdgcn_s_barrier();   // all waves done reading a0/b0; next iter's
    __builtin_amdgcn_sched_barrier(0);  // STAGE may overwrite rotated buffer

    unsigned short* ta = a0; a0 = a1; a1 = a2; a2 = ta;
    unsigned short* tb = b0; b0 = b1; b1 = b2; b2 = tb;
  }

  // epilogue: C/D layout col = lane&15, row = (lane>>4)*4 + j  (m89-verified)
  int fq = lane >> 4;
#pragma unroll
  for (int ni = 0; ni < 2; ++ni) {
    int gc = n0 + wn * 32 + ni * 16 + fr;
    float bv = bias[gc];
#pragma unroll
    for (int mi = 0; mi < 4; ++mi) {
      int gr = m0 + wm * 64 + mi * 16 + fq * 4;
#pragma unroll
      for (int j = 0; j < 4; ++j)
        C[(size_t)(gr + j) * N_DIM + gc] = acc[mi][ni][j] + bv;
    }
  }
#undef STAGE_A
#undef STAGE_B
}

extern "C" void kernel_launch(void* const* d_in, const int* in_sizes, int n_in,
                              void* d_out, int out_size, void* d_ws, size_t ws_size,
                              hipStream_t stream) {
  const float* x    = (const float*)d_in[0];
  const float* w    = (const float*)d_in[1];
  const float* b    = (const float*)d_in[2];
  const int*   indx = (const int*)d_in[3];
  float* out = (float*)d_out;

  // workspace: xb (8 MB) | wb (128 KB) | Bt (32 MB)
  unsigned short* xb = (unsigned short*)d_ws;
  unsigned short* wb = xb + (size_t)M_DIM * K_DIM;
  unsigned short* Bt = wb + NW;

  int prep_total = (M_DIM * K_DIM + NW) / 4;
  prep_kernel<<<(prep_total + 255) / 256, 256, 0, stream>>>(x, w, xb, wb);
  gather_kernel<<<256, 1024, 0, stream>>>(indx, wb, Bt);
  gemm_kernel<<<256, 512, 0, stream>>>(xb, Bt, b, out);
}